// Round 9
// baseline (96.242 us; speedup 1.0000x reference)
//
#include <hip/hip_runtime.h>
#include <cstdint>

#define B_ 2
#define N_ 8192
#define M_ 1024
#define C_ 1152
#define EPS_ 1e-8f
#define NT 32
#define CHUNK 128
#define NBN (N_ / NT)      // 256 n-blocks
#define NBC (C_ / CHUNK)   // 9 c-blocks
#define PTS 16             // points per threenn block
#define REDUN 4            // diagnosis: replicate work to crack rocprof top-5

typedef float f32x4 __attribute__((ext_vector_type(4)));

// bf16 helpers (RNE)
__device__ __forceinline__ unsigned short f2bf(float f) {
    unsigned u = __float_as_uint(f);
    u += 0x7fffu + ((u >> 16) & 1u);
    return (unsigned short)(u >> 16);
}
__device__ __forceinline__ float bf2f(unsigned short h) {
    return __uint_as_float(((unsigned)h) << 16);
}

// ---------------- K1: transpose feats [B][C][M] f32 -> fm [B][M][C] bf16 ----------------
__global__ __launch_bounds__(256) void k_transpose(const float* __restrict__ feats,
                                                   unsigned short* __restrict__ fm) {
    __shared__ float tile[64][65];
    int m0 = blockIdx.x * 64;
    int c0 = blockIdx.y * 64;
    int b  = blockIdx.z;
    int tx = threadIdx.x;
    int ty = threadIdx.y;
    const float* src = feats + ((size_t)b * C_ + c0) * M_ + m0;
#pragma unroll
    for (int j = 0; j < 16; ++j) {
        int cl = ty + 4 * j;
        tile[cl][tx] = __builtin_nontemporal_load(&src[(size_t)cl * M_ + tx]);
    }
    __syncthreads();
    unsigned short* dst = fm + ((size_t)b * M_ + m0) * C_ + c0;
#pragma unroll
    for (int j = 0; j < 16; ++j) {
        int ml = ty + 4 * j;
        dst[(size_t)ml * C_ + tx] = f2bf(tile[tx][ml]);
    }
}

// ---------------- K2: three_nn v5 logic, x4 redundant grid (diagnosis) ----------------
__device__ __forceinline__ void ins3(float d, int i,
        float& d0, int& i0, float& d1, int& i1, float& d2, int& i2) {
    bool b0 = d < d0;
    bool b1 = d < d1;
    bool b2 = d < d2;
    d2 = b1 ? d1 : (b2 ? d : d2);   i2 = b1 ? i1 : (b2 ? i : i2);
    d1 = b0 ? d0 : (b1 ? d : d1);   i1 = b0 ? i0 : (b1 ? i : i1);
    d0 = b0 ? d  : d0;              i0 = b0 ? i  : i0;
}
__device__ __forceinline__ void ins3lex(float d, int i,
        float& d0, int& i0, float& d1, int& i1, float& d2, int& i2) {
    bool b0 = (d < d0) || (d == d0 && i < i0);
    bool b1 = (d < d1) || (d == d1 && i < i1);
    bool b2 = (d < d2) || (d == d2 && i < i2);
    d2 = b1 ? d1 : (b2 ? d : d2);   i2 = b1 ? i1 : (b2 ? i : i2);
    d1 = b0 ? d0 : (b1 ? d : d1);   i1 = b0 ? i0 : (b1 ? i : i1);
    d0 = b0 ? d  : d0;              i0 = b0 ? i  : i0;
}

__global__ __launch_bounds__(256) void k_threenn(const float* __restrict__ xyz,
                                                 const float* __restrict__ center,
                                                 int* __restrict__ idx_ws,
                                                 float* __restrict__ w_ws) {
    __shared__ float4 sc[M_];   // 16 KB
    int b    = blockIdx.y;
    int unit = blockIdx.x >> 2;        // 4 replicas write identical values
    int n0   = unit * PTS;
    int t    = threadIdx.x;
    for (int i = t; i < M_; i += 256) {
        float cx = center[((size_t)b * M_ + i) * 3 + 0];
        float cy = center[((size_t)b * M_ + i) * 3 + 1];
        float cz = center[((size_t)b * M_ + i) * 3 + 2];
        // ref: sum(center*center,-1): rounded squares, left-assoc, no fma
        float cc = __fadd_rn(__fadd_rn(__fmul_rn(cx, cx), __fmul_rn(cy, cy)),
                             __fmul_rn(cz, cz));
        sc[i] = make_float4(cx, cy, cz, cc);
    }
    __syncthreads();

    int p = t >> 4;     // 0..15: point within block
    int c = t & 15;     // 0..15: chunk
    int n = n0 + p;
    float x = xyz[((size_t)b * N_ + n) * 3 + 0];
    float y = xyz[((size_t)b * N_ + n) * 3 + 1];
    float z = xyz[((size_t)b * N_ + n) * 3 + 2];
    float xx = __fadd_rn(__fadd_rn(__fmul_rn(x, x), __fmul_rn(y, y)),
                         __fmul_rn(z, z));

    float d0 = __builtin_inff(), d1 = __builtin_inff(), d2 = __builtin_inff();
    int   i0 = 0x7fffffff,  i1 = 0x7fffffff,  i2 = 0x7fffffff;
#pragma unroll 4
    for (int it = 0; it < M_ / 16; ++it) {
        int m = c + it * 16;                 // increasing per lane -> strict < stable
        float4 v = sc[m];
        // ref einsum: fma-accumulated dot;  d = (xx+cc) - 2*dot  (bit-exact)
        float dot = __fmaf_rn(z, v.z, __fmaf_rn(y, v.y, __fmul_rn(x, v.x)));
        float d   = __fsub_rn(__fadd_rn(xx, v.w), __fmul_rn(2.0f, dot));
        ins3(d, m, d0, i0, d1, i1, d2, i2);
    }
#pragma unroll
    for (int off = 1; off <= 8; off <<= 1) {
        float e0 = __shfl_xor(d0, off); int j0 = __shfl_xor(i0, off);
        float e1 = __shfl_xor(d1, off); int j1 = __shfl_xor(i1, off);
        float e2 = __shfl_xor(d2, off); int j2 = __shfl_xor(i2, off);
        ins3lex(e0, j0, d0, i0, d1, i1, d2, i2);
        ins3lex(e1, j1, d0, i0, d1, i1, d2, i2);
        ins3lex(e2, j2, d0, i0, d1, i1, d2, i2);
    }
    if (c == 0) {
        float r0 = 1.0f / __fadd_rn(d0, EPS_);
        float r1 = 1.0f / __fadd_rn(d1, EPS_);
        float r2 = 1.0f / __fadd_rn(d2, EPS_);
        float s  = __fadd_rn(__fadd_rn(r0, r1), r2);
        size_t base = ((size_t)b * N_ + n) * 3;
        idx_ws[base + 0] = i0; idx_ws[base + 1] = i1; idx_ws[base + 2] = i2;
        w_ws[base + 0] = r0 / s; w_ws[base + 1] = r1 / s; w_ws[base + 2] = r2 / s;
    }
}

// ---------------- K3: interp, x4 redundant grid (diagnosis) ----------------
__global__ __launch_bounds__(256) void k_interp(const unsigned short* __restrict__ fm,
                                                const int* __restrict__ idx_ws,
                                                const float* __restrict__ w_ws,
                                                float* __restrict__ out) {
    __shared__ float T[NT][CHUNK + 1];   // stride 129
    __shared__ int   sbase[NT][3];
    __shared__ float sw[NT][3];
    int unit = blockIdx.x >> 2;                // 4 replicas write identical values
    int slot = unit & 7;
    int b    = slot >> 2;
    int idx  = (unit >> 3) * 4 + (slot & 3);   // 0..2303 per batch
    int n0   = (idx & (NBN - 1)) * NT;
    int c0   = (idx >> 8) * CHUNK;
    int t    = threadIdx.x;
    if (t < NT) {
        size_t ib = ((size_t)b * N_ + n0 + t) * 3;
#pragma unroll
        for (int k = 0; k < 3; ++k) {
            sbase[t][k] = (b * M_ + idx_ws[ib + k]) * C_;
            sw[t][k]    = w_ws[ib + k];
        }
    }
    __syncthreads();
    int wave = t >> 6;
    int lane = t & 63;
    int half = lane >> 5;
    int cl   = (lane & 31) * 4;
#pragma unroll
    for (int pp = 0; pp < 4; ++pp) {
        int p = pp * 8 + wave * 2 + half;
        float w0 = sw[p][0], w1 = sw[p][1], w2 = sw[p][2];
        const ushort4 a0 = *(const ushort4*)(fm + sbase[p][0] + c0 + cl);
        const ushort4 a1 = *(const ushort4*)(fm + sbase[p][1] + c0 + cl);
        const ushort4 a2 = *(const ushort4*)(fm + sbase[p][2] + c0 + cl);
        T[p][cl + 0] = __fmaf_rn(bf2f(a2.x), w2, __fmaf_rn(bf2f(a1.x), w1, __fmul_rn(bf2f(a0.x), w0)));
        T[p][cl + 1] = __fmaf_rn(bf2f(a2.y), w2, __fmaf_rn(bf2f(a1.y), w1, __fmul_rn(bf2f(a0.y), w0)));
        T[p][cl + 2] = __fmaf_rn(bf2f(a2.z), w2, __fmaf_rn(bf2f(a1.z), w1, __fmul_rn(bf2f(a0.z), w0)));
        T[p][cl + 3] = __fmaf_rn(bf2f(a2.w), w2, __fmaf_rn(bf2f(a1.w), w1, __fmul_rn(bf2f(a0.w), w0)));
    }
    __syncthreads();
    int p4  = (t & 7) * 4;
    int ccb = t >> 3;
#pragma unroll
    for (int r = 0; r < 4; ++r) {
        int cc = r * 32 + ccb;
        f32x4 v = { T[p4 + 0][cc], T[p4 + 1][cc], T[p4 + 2][cc], T[p4 + 3][cc] };
        __builtin_nontemporal_store(v,
            (f32x4*)&out[((size_t)b * C_ + c0 + cc) * N_ + n0 + p4]);
    }
}

// ---------------- launch ----------------
extern "C" void kernel_launch(void* const* d_in, const int* in_sizes, int n_in,
                              void* d_out, int out_size, void* d_ws, size_t ws_size,
                              hipStream_t stream) {
    const float* xyz    = (const float*)d_in[0];   // [B,N,3]
    const float* center = (const float*)d_in[1];   // [B,M,3]
    const float* feats  = (const float*)d_in[2];   // [B,C,M]
    float* out = (float*)d_out;                    // [B,C,N]

    char*           ws     = (char*)d_ws;
    unsigned short* fm     = (unsigned short*)ws;
    int*            idx_ws = (int*)(ws + (size_t)B_ * M_ * C_ * 2);
    float*          w_ws   = (float*)(ws + (size_t)B_ * M_ * C_ * 2 + (size_t)B_ * N_ * 3 * 4);

    k_transpose<<<dim3(M_ / 64, C_ / 64, B_), dim3(64, 4), 0, stream>>>(feats, fm);
    k_threenn <<<dim3(REDUN * (N_ / PTS), B_), 256, 0, stream>>>(xyz, center, idx_ws, w_ws);
    k_interp  <<<REDUN * NBN * NBC * B_, 256, 0, stream>>>(fm, idx_ws, w_ws, out);
}

// Round 10
// 52.435 us; speedup vs baseline: 1.8354x; 1.8354x over previous
//
#include <hip/hip_runtime.h>
#include <cstdint>

#define B_ 2
#define N_ 8192
#define M_ 1024
#define C_ 1152
#define EPS_ 1e-8f
#define NT 32
#define CHUNK 128
#define NBN (N_ / NT)      // 256 n-blocks
#define NBC (C_ / CHUNK)   // 9 c-blocks
#define TRB ((M_ / 64) * (C_ / 64) * B_)   // 576 transpose blocks
#define PTS 32             // points per threenn block (4 per thread)

typedef float f32x4 __attribute__((ext_vector_type(4)));

// bf16 helpers (RNE)
__device__ __forceinline__ unsigned short f2bf(float f) {
    unsigned u = __float_as_uint(f);
    u += 0x7fffu + ((u >> 16) & 1u);
    return (unsigned short)(u >> 16);
}
__device__ __forceinline__ float bf2f(unsigned short h) {
    return __uint_as_float(((unsigned)h) << 16);
}

// position-insert, strict < (stable when per-lane index stream is increasing)
__device__ __forceinline__ void ins3(float d, int i,
        float& d0, int& i0, float& d1, int& i1, float& d2, int& i2) {
    bool b0 = d < d0;
    bool b1 = d < d1;
    bool b2 = d < d2;
    d2 = b1 ? d1 : (b2 ? d : d2);   i2 = b1 ? i1 : (b2 ? i : i2);
    d1 = b0 ? d0 : (b1 ? d : d1);   i1 = b0 ? i0 : (b1 ? i : i1);
    d0 = b0 ? d  : d0;              i0 = b0 ? i  : i0;
}
// cross-lane merge insert: lexicographic (d, then index)
__device__ __forceinline__ void ins3lex(float d, int i,
        float& d0, int& i0, float& d1, int& i1, float& d2, int& i2) {
    bool b0 = (d < d0) || (d == d0 && i < i0);
    bool b1 = (d < d1) || (d == d1 && i < i1);
    bool b2 = (d < d2) || (d == d2 && i < i2);
    d2 = b1 ? d1 : (b2 ? d : d2);   i2 = b1 ? i1 : (b2 ? i : i2);
    d1 = b0 ? d0 : (b1 ? d : d1);   i1 = b0 ? i0 : (b1 ? i : i1);
    d0 = b0 ? d  : d0;              i0 = b0 ? i  : i0;
}

// ---------------- K_prep: transpose feats -> bf16 fm, + pack center table ----------------
__global__ __launch_bounds__(256) void k_prep(const float* __restrict__ feats,
                                              unsigned short* __restrict__ fm,
                                              const float* __restrict__ center,
                                              float4* __restrict__ cpk) {
    __shared__ float tile[64][65];
    int bid = blockIdx.x;
    int t   = threadIdx.x;

    if (bid >= TRB) {
        // ---- pack role: center [B][M][3] -> cpk [B][M] float4{x,y,z,|c|^2} ----
        int b = bid - TRB;            // 0..1
        for (int i = t; i < M_; i += 256) {
            float cx = center[((size_t)b * M_ + i) * 3 + 0];
            float cy = center[((size_t)b * M_ + i) * 3 + 1];
            float cz = center[((size_t)b * M_ + i) * 3 + 2];
            // ref: sum(center*center,-1): rounded squares, left-assoc, no fma
            float cc = __fadd_rn(__fadd_rn(__fmul_rn(cx, cx), __fmul_rn(cy, cy)),
                                 __fmul_rn(cz, cz));
            cpk[b * M_ + i] = make_float4(cx, cy, cz, cc);
        }
        return;
    }

    // ---- transpose role ----
    int within = bid % ((M_ / 64) * (C_ / 64));
    int b  = bid / ((M_ / 64) * (C_ / 64));
    int mb = within & 15;
    int cb = within >> 4;
    int m0 = mb * 64;
    int c0 = cb * 64;
    int tx = t & 63;
    int ty = t >> 6;
    const float* src = feats + ((size_t)b * C_ + c0) * M_ + m0;
#pragma unroll
    for (int j = 0; j < 16; ++j) {
        int cl = ty + 4 * j;
        tile[cl][tx] = __builtin_nontemporal_load(&src[(size_t)cl * M_ + tx]);
    }
    __syncthreads();
    unsigned short* dst = fm + ((size_t)b * M_ + m0) * C_ + c0;
#pragma unroll
    for (int j = 0; j < 16; ++j) {
        int ml = ty + 4 * j;
        dst[(size_t)ml * C_ + tx] = f2bf(tile[tx][ml]);
    }
}

// ---------------- K2: three_nn v6 — 4 points/thread, centers from L1/L2, no LDS ----------------
__global__ __launch_bounds__(256) void k_threenn(const float* __restrict__ xyz,
                                                 const float4* __restrict__ cpk,
                                                 int* __restrict__ idx_ws,
                                                 float* __restrict__ w_ws) {
    int b  = blockIdx.y;
    int n0 = blockIdx.x * PTS;
    int t  = threadIdx.x;
    int c  = t & 31;              // 32-center interleaved chunk lane
    int q  = t >> 5;              // 0..7: point-quad within block
    int n  = n0 + q * 4;          // first of this thread's 4 consecutive points

    // load 4 points' xyz (12 consecutive floats, 16B-aligned since n%4==0)
    const float* xp = xyz + ((size_t)b * N_ + n) * 3;
    f32x4 v0 = *(const f32x4*)(xp);
    f32x4 v1 = *(const f32x4*)(xp + 4);
    f32x4 v2 = *(const f32x4*)(xp + 8);
    float px[4], py[4], pz[4], pxx[4];
    px[0] = v0.x; py[0] = v0.y; pz[0] = v0.z;
    px[1] = v0.w; py[1] = v1.x; pz[1] = v1.y;
    px[2] = v1.z; py[2] = v1.w; pz[2] = v2.x;
    px[3] = v2.y; py[3] = v2.z; pz[3] = v2.w;
#pragma unroll
    for (int k = 0; k < 4; ++k)
        pxx[k] = __fadd_rn(__fadd_rn(__fmul_rn(px[k], px[k]), __fmul_rn(py[k], py[k])),
                           __fmul_rn(pz[k], pz[k]));

    float d0[4], d1[4], d2[4];
    int   i0[4], i1[4], i2[4];
#pragma unroll
    for (int k = 0; k < 4; ++k) {
        d0[k] = d1[k] = d2[k] = __builtin_inff();
        i0[k] = i1[k] = i2[k] = 0x7fffffff;
    }

    const float4* cb = cpk + b * M_ + c;   // lane's chunk base, stride 32
    float4 cur = cb[0];
#pragma unroll 5
    for (int it = 0; it < 31; ++it) {
        float4 nxt = cb[(it + 1) * 32];    // prefetch next center (L1-resident table)
        int m = c + it * 32;               // increasing per lane -> strict < stable
#pragma unroll
        for (int k = 0; k < 4; ++k) {
            // ref einsum: fma dot;  d = (xx+cc) - 2*dot  (bit-exact vs R8)
            float dot = __fmaf_rn(pz[k], cur.z, __fmaf_rn(py[k], cur.y, __fmul_rn(px[k], cur.x)));
            float d   = __fsub_rn(__fadd_rn(pxx[k], cur.w), __fmul_rn(2.0f, dot));
            ins3(d, m, d0[k], i0[k], d1[k], i1[k], d2[k], i2[k]);
        }
        cur = nxt;
    }
    {
        int m = c + 31 * 32;
#pragma unroll
        for (int k = 0; k < 4; ++k) {
            float dot = __fmaf_rn(pz[k], cur.z, __fmaf_rn(py[k], cur.y, __fmul_rn(px[k], cur.x)));
            float d   = __fsub_rn(__fadd_rn(pxx[k], cur.w), __fmul_rn(2.0f, dot));
            ins3(d, m, d0[k], i0[k], d1[k], i1[k], d2[k], i2[k]);
        }
    }

    // 5-round butterfly merge over the 32 chunk lanes (xor<=16 stays in half-wave)
#pragma unroll
    for (int off = 1; off <= 16; off <<= 1) {
#pragma unroll
        for (int k = 0; k < 4; ++k) {
            float e0 = __shfl_xor(d0[k], off); int j0 = __shfl_xor(i0[k], off);
            float e1 = __shfl_xor(d1[k], off); int j1 = __shfl_xor(i1[k], off);
            float e2 = __shfl_xor(d2[k], off); int j2 = __shfl_xor(i2[k], off);
            ins3lex(e0, j0, d0[k], i0[k], d1[k], i1[k], d2[k], i2[k]);
            ins3lex(e1, j1, d0[k], i0[k], d1[k], i1[k], d2[k], i2[k]);
            ins3lex(e2, j2, d0[k], i0[k], d1[k], i1[k], d2[k], i2[k]);
        }
    }

    if (c == 0) {
#pragma unroll
        for (int k = 0; k < 4; ++k) {
            float r0 = 1.0f / __fadd_rn(d0[k], EPS_);
            float r1 = 1.0f / __fadd_rn(d1[k], EPS_);
            float r2 = 1.0f / __fadd_rn(d2[k], EPS_);
            float s  = __fadd_rn(__fadd_rn(r0, r1), r2);
            size_t base = ((size_t)b * N_ + n + k) * 3;
            idx_ws[base + 0] = i0[k]; idx_ws[base + 1] = i1[k]; idx_ws[base + 2] = i2[k];
            w_ws[base + 0] = r0 / s; w_ws[base + 1] = r1 / s; w_ws[base + 2] = r2 / s;
        }
    }
}

// ---------------- K3: gather(bf16,ushort4) + weighted sum; XCD-pinned 1D grid ----------------
__global__ __launch_bounds__(256) void k_interp(const unsigned short* __restrict__ fm,
                                                const int* __restrict__ idx_ws,
                                                const float* __restrict__ w_ws,
                                                float* __restrict__ out) {
    __shared__ float T[NT][CHUNK + 1];   // stride 129
    __shared__ int   sbase[NT][3];
    __shared__ float sw[NT][3];
    int flat = blockIdx.x;
    int slot = flat & 7;
    int b    = slot >> 2;
    int idx  = (flat >> 3) * 4 + (slot & 3);   // 0..2303 per batch
    int n0   = (idx & (NBN - 1)) * NT;
    int c0   = (idx >> 8) * CHUNK;
    int t    = threadIdx.x;
    if (t < NT) {
        size_t ib = ((size_t)b * N_ + n0 + t) * 3;
#pragma unroll
        for (int k = 0; k < 3; ++k) {
            sbase[t][k] = (b * M_ + idx_ws[ib + k]) * C_;
            sw[t][k]    = w_ws[ib + k];
        }
    }
    __syncthreads();
    int wave = t >> 6;
    int lane = t & 63;
    int half = lane >> 5;
    int cl   = (lane & 31) * 4;
#pragma unroll
    for (int pp = 0; pp < 4; ++pp) {
        int p = pp * 8 + wave * 2 + half;
        float w0 = sw[p][0], w1 = sw[p][1], w2 = sw[p][2];
        const ushort4 a0 = *(const ushort4*)(fm + sbase[p][0] + c0 + cl);
        const ushort4 a1 = *(const ushort4*)(fm + sbase[p][1] + c0 + cl);
        const ushort4 a2 = *(const ushort4*)(fm + sbase[p][2] + c0 + cl);
        T[p][cl + 0] = __fmaf_rn(bf2f(a2.x), w2, __fmaf_rn(bf2f(a1.x), w1, __fmul_rn(bf2f(a0.x), w0)));
        T[p][cl + 1] = __fmaf_rn(bf2f(a2.y), w2, __fmaf_rn(bf2f(a1.y), w1, __fmul_rn(bf2f(a0.y), w0)));
        T[p][cl + 2] = __fmaf_rn(bf2f(a2.z), w2, __fmaf_rn(bf2f(a1.z), w1, __fmul_rn(bf2f(a0.z), w0)));
        T[p][cl + 3] = __fmaf_rn(bf2f(a2.w), w2, __fmaf_rn(bf2f(a1.w), w1, __fmul_rn(bf2f(a0.w), w0)));
    }
    __syncthreads();
    int p4  = (t & 7) * 4;
    int ccb = t >> 3;
#pragma unroll
    for (int r = 0; r < 4; ++r) {
        int cc = r * 32 + ccb;
        f32x4 v = { T[p4 + 0][cc], T[p4 + 1][cc], T[p4 + 2][cc], T[p4 + 3][cc] };
        __builtin_nontemporal_store(v,
            (f32x4*)&out[((size_t)b * C_ + c0 + cc) * N_ + n0 + p4]);
    }
}

// ---------------- launch ----------------
extern "C" void kernel_launch(void* const* d_in, const int* in_sizes, int n_in,
                              void* d_out, int out_size, void* d_ws, size_t ws_size,
                              hipStream_t stream) {
    const float* xyz    = (const float*)d_in[0];   // [B,N,3]
    const float* center = (const float*)d_in[1];   // [B,M,3]
    const float* feats  = (const float*)d_in[2];   // [B,C,M]
    float* out = (float*)d_out;                    // [B,C,N]

    // ws: fm bf16 | idx i32 | w f32 | cpk float4   (~5.14 MB)
    char*           ws     = (char*)d_ws;
    unsigned short* fm     = (unsigned short*)ws;
    size_t off = (size_t)B_ * M_ * C_ * 2;
    int*            idx_ws = (int*)(ws + off);      off += (size_t)B_ * N_ * 3 * 4;
    float*          w_ws   = (float*)(ws + off);    off += (size_t)B_ * N_ * 3 * 4;
    float4*         cpk    = (float4*)(ws + off);

    k_prep   <<<TRB + B_, 256, 0, stream>>>(feats, fm, center, cpk);
    k_threenn<<<dim3(N_ / PTS, B_), 256, 0, stream>>>(xyz, cpk, idx_ws, w_ws);
    k_interp <<<NBN * NBC * B_, 256, 0, stream>>>(fm, idx_ws, w_ws, out);
}

// Round 11
// 37.119 us; speedup vs baseline: 2.5928x; 1.4126x over previous
//
#include <hip/hip_runtime.h>
#include <cstdint>

#define B_ 2
#define N_ 8192
#define M_ 1024
#define C_ 1152
#define EPS_ 1e-8f
#define NT 32
#define CHUNK 128
#define NBN (N_ / NT)      // 256 n-blocks
#define NBC (C_ / CHUNK)   // 9 c-blocks
#define PTS 16             // points per threenn block
#define TRB ((M_ / 64) * (C_ / 64) * B_)   // 576 transpose blocks

typedef float f32x4 __attribute__((ext_vector_type(4)));

// bf16 helpers (RNE)
__device__ __forceinline__ unsigned short f2bf(float f) {
    unsigned u = __float_as_uint(f);
    u += 0x7fffu + ((u >> 16) & 1u);
    return (unsigned short)(u >> 16);
}
__device__ __forceinline__ float bf2f(unsigned short h) {
    return __uint_as_float(((unsigned)h) << 16);
}

// position-insert, strict < (stable when per-lane index stream is increasing)
__device__ __forceinline__ void ins3(float d, int i,
        float& d0, int& i0, float& d1, int& i1, float& d2, int& i2) {
    bool b0 = d < d0;
    bool b1 = d < d1;
    bool b2 = d < d2;
    d2 = b1 ? d1 : (b2 ? d : d2);   i2 = b1 ? i1 : (b2 ? i : i2);
    d1 = b0 ? d0 : (b1 ? d : d1);   i1 = b0 ? i0 : (b1 ? i : i1);
    d0 = b0 ? d  : d0;              i0 = b0 ? i  : i0;
}
// cross-lane merge insert: lexicographic (d, then index)
__device__ __forceinline__ void ins3lex(float d, int i,
        float& d0, int& i0, float& d1, int& i1, float& d2, int& i2) {
    bool b0 = (d < d0) || (d == d0 && i < i0);
    bool b1 = (d < d1) || (d == d1 && i < i1);
    bool b2 = (d < d2) || (d == d2 && i < i2);
    d2 = b1 ? d1 : (b2 ? d : d2);   i2 = b1 ? i1 : (b2 ? i : i2);
    d1 = b0 ? d0 : (b1 ? d : d1);   i1 = b0 ? i0 : (b1 ? i : i1);
    d0 = b0 ? d  : d0;              i0 = b0 ? i  : i0;
}

// ---------------- K_front: fused transpose (blocks 0..TRB-1) + three_nn v7 (rest) ----------------
__global__ __launch_bounds__(256, 4) void k_front(const float* __restrict__ feats,
                                                  unsigned short* __restrict__ fm,
                                                  const float* __restrict__ xyz,
                                                  const float* __restrict__ center,
                                                  int* __restrict__ idx_ws,
                                                  float* __restrict__ w_ws) {
    __shared__ float4 sc[1040];   // 16.64 KB; transpose aliases it as float[64*65]
    int bid = blockIdx.x;
    int t   = threadIdx.x;

    if (bid < TRB) {
        // ---- transpose role: feats [B][C][M] f32 -> fm [B][M][C] bf16 ----
        float* tile = (float*)sc;            // [64][65]
        int within = bid % ((M_ / 64) * (C_ / 64));
        int b  = bid / ((M_ / 64) * (C_ / 64));
        int mb = within & 15;
        int cb = within >> 4;                // 0..17
        int m0 = mb * 64;
        int c0 = cb * 64;
        int tx = t & 63;
        int ty = t >> 6;                     // 0..3
        const float* src = feats + ((size_t)b * C_ + c0) * M_ + m0;
#pragma unroll
        for (int j = 0; j < 16; ++j) {
            int cl = ty + 4 * j;
            tile[cl * 65 + tx] = __builtin_nontemporal_load(&src[(size_t)cl * M_ + tx]);
        }
        __syncthreads();
        unsigned short* dst = fm + ((size_t)b * M_ + m0) * C_ + c0;
#pragma unroll
        for (int j = 0; j < 16; ++j) {
            int ml = ty + 4 * j;
            dst[(size_t)ml * C_ + tx] = f2bf(tile[tx * 65 + ml]);
        }
        return;
    }

    // ---- three_nn v7: v5 geometry + explicit 4-deep register pipeline ----
    int flat = bid - TRB;                    // 0..1023
    int b    = flat >> 9;                    // 512 blocks per batch
    int n0   = (flat & 511) * PTS;
    for (int i = t; i < M_; i += 256) {
        float cx = center[((size_t)b * M_ + i) * 3 + 0];
        float cy = center[((size_t)b * M_ + i) * 3 + 1];
        float cz = center[((size_t)b * M_ + i) * 3 + 2];
        // ref: sum(center*center,-1): rounded squares, left-assoc, no fma
        float cc = __fadd_rn(__fadd_rn(__fmul_rn(cx, cx), __fmul_rn(cy, cy)),
                             __fmul_rn(cz, cz));
        sc[i] = make_float4(cx, cy, cz, cc);
    }
    __syncthreads();

    int p = t >> 4;     // 0..15: point within block
    int c = t & 15;     // 0..15: chunk
    int n = n0 + p;
    float x = xyz[((size_t)b * N_ + n) * 3 + 0];
    float y = xyz[((size_t)b * N_ + n) * 3 + 1];
    float z = xyz[((size_t)b * N_ + n) * 3 + 2];
    float xx = __fadd_rn(__fadd_rn(__fmul_rn(x, x), __fmul_rn(y, y)),
                         __fmul_rn(z, z));

    float d0 = __builtin_inff(), d1 = __builtin_inff(), d2 = __builtin_inff();
    int   i0 = 0x7fffffff,  i1 = 0x7fffffff,  i2 = 0x7fffffff;

    // ref einsum: fma dot;  d = (xx+cc) - 2*dot  (bit-exact vs R8)
#define PROC(v, mm) do { \
        float dot_ = __fmaf_rn(z, (v).z, __fmaf_rn(y, (v).y, __fmul_rn(x, (v).x))); \
        float dd_  = __fsub_rn(__fadd_rn(xx, (v).w), __fmul_rn(2.0f, dot_)); \
        ins3(dd_, (mm), d0, i0, d1, i1, d2, i2); \
    } while (0)

    // iter it reads sc[c + it*16], m = c + it*16; groups of 4 iters,
    // next group's 4 ds_read_b128 issued before processing current group.
    const float4* lb = sc + c;
    float4 r0 = lb[0], r1 = lb[16], r2 = lb[32], r3 = lb[48];
    for (int g = 0; g < 15; ++g) {
        const float4* nb = lb + (g + 1) * 64;
        float4 n0v = nb[0], n1v = nb[16], n2v = nb[32], n3v = nb[48];
        int mb = c + g * 64;
        PROC(r0, mb); PROC(r1, mb + 16); PROC(r2, mb + 32); PROC(r3, mb + 48);
        r0 = n0v; r1 = n1v; r2 = n2v; r3 = n3v;
    }
    PROC(r0, c + 960); PROC(r1, c + 976); PROC(r2, c + 992); PROC(r3, c + 1008);
#undef PROC

    // 4-round butterfly merge within the 16-lane group (lexicographic)
#pragma unroll
    for (int off = 1; off <= 8; off <<= 1) {
        float e0 = __shfl_xor(d0, off); int j0 = __shfl_xor(i0, off);
        float e1 = __shfl_xor(d1, off); int j1 = __shfl_xor(i1, off);
        float e2 = __shfl_xor(d2, off); int j2 = __shfl_xor(i2, off);
        ins3lex(e0, j0, d0, i0, d1, i1, d2, i2);
        ins3lex(e1, j1, d0, i0, d1, i1, d2, i2);
        ins3lex(e2, j2, d0, i0, d1, i1, d2, i2);
    }
    if (c == 0) {
        float r0w = 1.0f / __fadd_rn(d0, EPS_);
        float r1w = 1.0f / __fadd_rn(d1, EPS_);
        float r2w = 1.0f / __fadd_rn(d2, EPS_);
        float s   = __fadd_rn(__fadd_rn(r0w, r1w), r2w);
        size_t base = ((size_t)b * N_ + n) * 3;
        idx_ws[base + 0] = i0; idx_ws[base + 1] = i1; idx_ws[base + 2] = i2;
        w_ws[base + 0] = r0w / s; w_ws[base + 1] = r1w / s; w_ws[base + 2] = r2w / s;
    }
}

// ---------------- K_interp: gather(bf16,ushort4) + weighted sum; XCD-pinned 1D grid ----------------
__global__ __launch_bounds__(256) void k_interp(const unsigned short* __restrict__ fm,
                                                const int* __restrict__ idx_ws,
                                                const float* __restrict__ w_ws,
                                                float* __restrict__ out) {
    __shared__ float T[NT][CHUNK + 1];   // stride 129
    __shared__ int   sbase[NT][3];
    __shared__ float sw[NT][3];
    int flat = blockIdx.x;
    int slot = flat & 7;
    int b    = slot >> 2;
    int idx  = (flat >> 3) * 4 + (slot & 3);   // 0..2303 per batch
    int n0   = (idx & (NBN - 1)) * NT;
    int c0   = (idx >> 8) * CHUNK;
    int t    = threadIdx.x;
    if (t < NT) {
        size_t ib = ((size_t)b * N_ + n0 + t) * 3;
#pragma unroll
        for (int k = 0; k < 3; ++k) {
            sbase[t][k] = (b * M_ + idx_ws[ib + k]) * C_;
            sw[t][k]    = w_ws[ib + k];
        }
    }
    __syncthreads();
    int wave = t >> 6;
    int lane = t & 63;
    int half = lane >> 5;
    int cl   = (lane & 31) * 4;
#pragma unroll
    for (int pp = 0; pp < 4; ++pp) {
        int p = pp * 8 + wave * 2 + half;
        float w0 = sw[p][0], w1 = sw[p][1], w2 = sw[p][2];
        const ushort4 a0 = *(const ushort4*)(fm + sbase[p][0] + c0 + cl);
        const ushort4 a1 = *(const ushort4*)(fm + sbase[p][1] + c0 + cl);
        const ushort4 a2 = *(const ushort4*)(fm + sbase[p][2] + c0 + cl);
        T[p][cl + 0] = __fmaf_rn(bf2f(a2.x), w2, __fmaf_rn(bf2f(a1.x), w1, __fmul_rn(bf2f(a0.x), w0)));
        T[p][cl + 1] = __fmaf_rn(bf2f(a2.y), w2, __fmaf_rn(bf2f(a1.y), w1, __fmul_rn(bf2f(a0.y), w0)));
        T[p][cl + 2] = __fmaf_rn(bf2f(a2.z), w2, __fmaf_rn(bf2f(a1.z), w1, __fmul_rn(bf2f(a0.z), w0)));
        T[p][cl + 3] = __fmaf_rn(bf2f(a2.w), w2, __fmaf_rn(bf2f(a1.w), w1, __fmul_rn(bf2f(a0.w), w0)));
    }
    __syncthreads();
    int p4  = (t & 7) * 4;
    int ccb = t >> 3;
#pragma unroll
    for (int r = 0; r < 4; ++r) {
        int cc = r * 32 + ccb;
        f32x4 v = { T[p4 + 0][cc], T[p4 + 1][cc], T[p4 + 2][cc], T[p4 + 3][cc] };
        __builtin_nontemporal_store(v,
            (f32x4*)&out[((size_t)b * C_ + c0 + cc) * N_ + n0 + p4]);
    }
}

// ---------------- launch ----------------
extern "C" void kernel_launch(void* const* d_in, const int* in_sizes, int n_in,
                              void* d_out, int out_size, void* d_ws, size_t ws_size,
                              hipStream_t stream) {
    const float* xyz    = (const float*)d_in[0];   // [B,N,3]
    const float* center = (const float*)d_in[1];   // [B,M,3]
    const float* feats  = (const float*)d_in[2];   // [B,C,M]
    float* out = (float*)d_out;                    // [B,C,N]

    char*           ws     = (char*)d_ws;
    unsigned short* fm     = (unsigned short*)ws;
    int*            idx_ws = (int*)(ws + (size_t)B_ * M_ * C_ * 2);
    float*          w_ws   = (float*)(ws + (size_t)B_ * M_ * C_ * 2 + (size_t)B_ * N_ * 3 * 4);

    k_front <<<TRB + (N_ / PTS) * B_, 256, 0, stream>>>(feats, fm, xyz, center, idx_ws, w_ws);
    k_interp<<<NBN * NBC * B_, 256, 0, stream>>>(fm, idx_ws, w_ws, out);
}